// Round 6
// baseline (231.609 us; speedup 1.0000x reference)
//
#include <hip/hip_runtime.h>
#include <math.h>

#define BB 8
#define SS 160
#define HH 768
#define DEPTH 64
#define NHEAD 12
#define DHEAD 64
#define BS (BB*SS)

constexpr float EPS_C = 1e-5f;

// ---------------- Projection: q,kT,v = X @ W + b ----------------
// k is written TRANSPOSED: kT[b][ch][j] so attn's score loop reads are
// coalesced. Each proj thread holds 16 consecutive rows of one column in
// registers -> contiguous 16-float store per thread.
__global__ __launch_bounds__(256) void proj_qkv(
    const float* __restrict__ X,
    const float* __restrict__ Wq, const float* __restrict__ bq,
    const float* __restrict__ Wk, const float* __restrict__ bk,
    const float* __restrict__ Wv, const float* __restrict__ bv,
    float* __restrict__ q, float* __restrict__ kT, float* __restrict__ v)
{
    __shared__ float sxT[HH * 16];   // 48 KB: sxT[c*16 + r]
    int bx = blockIdx.x;
    int rt = bx / 9, rem = bx % 9;
    int m = rem / 3, ct = rem % 3;
    int row0 = rt * 16;
    const float* W    = (m == 0) ? Wq : (m == 1) ? Wk : Wv;
    const float* bias = (m == 0) ? bq : (m == 1) ? bk : bv;

    for (int idx = threadIdx.x; idx < 16 * HH; idx += 256) {
        int r = idx / HH, c = idx - r * HH;
        sxT[c * 16 + r] = X[(row0 + r) * HH + c];
    }
    __syncthreads();

    int col = ct * 256 + threadIdx.x;
    float acc[16];
#pragma unroll
    for (int r = 0; r < 16; r++) acc[r] = 0.f;

    const float* Wp = W + col;
    for (int c = 0; c < HH; c++) {
        float wv = Wp[(size_t)c * HH];
        const float4* xp = (const float4*)(&sxT[c * 16]);
        float4 x0 = xp[0], x1 = xp[1], x2 = xp[2], x3 = xp[3];
        acc[0]  += x0.x * wv;  acc[1]  += x0.y * wv;
        acc[2]  += x0.z * wv;  acc[3]  += x0.w * wv;
        acc[4]  += x1.x * wv;  acc[5]  += x1.y * wv;
        acc[6]  += x1.z * wv;  acc[7]  += x1.w * wv;
        acc[8]  += x2.x * wv;  acc[9]  += x2.y * wv;
        acc[10] += x2.z * wv;  acc[11] += x2.w * wv;
        acc[12] += x3.x * wv;  acc[13] += x3.y * wv;
        acc[14] += x3.z * wv;  acc[15] += x3.w * wv;
    }
    float bb = bias[col];
    if (m == 1) {
        int b  = row0 / SS, i0 = row0 - (row0 / SS) * SS;
        float* dst = kT + ((size_t)b * HH + col) * SS + i0;
#pragma unroll
        for (int r = 0; r < 16; r++) dst[r] = acc[r] + bb;   // 64B contiguous
    } else {
        float* out = (m == 0) ? q : v;
#pragma unroll
        for (int r = 0; r < 16; r++) out[(size_t)(row0 + r) * HH + col] = acc[r] + bb;
    }
}

// ---------------- Fused attention + edge terms + LayerNorm ----------------
// One block per (b, i) query row. 256 threads = 4 waves.
// __launch_bounds__(256,8): cap VGPR at 64 so 5+ blocks/CU are resident
// (grid 1280 = 5*256 -> single scheduling round, no straggler tail).
__global__ __launch_bounds__(256, 8) void attn_kernel(
    const float* __restrict__ token, const float* __restrict__ edge,
    const int* __restrict__ mask,
    const float* __restrict__ q_ws, const float* __restrict__ kT,
    const float* __restrict__ v_ws,
    const float* __restrict__ Wek, const float* __restrict__ bek,
    const float* __restrict__ Wev, const float* __restrict__ bev,
    const float* __restrict__ ln_g, const float* __restrict__ ln_b,
    float* __restrict__ out)
{
    __shared__ alignas(16) float  s_q[HH];               // q row; ctx_v later
    __shared__ alignas(16) float  s_qek[NHEAD * DEPTH];  // Wek_h^T q_h
    __shared__ float  s_qbek[NHEAD];
    __shared__ alignas(16) float  s_pool[32 * 66];       // e tile; s_x later
    __shared__ alignas(16) float  s_scores[NHEAD][SS];   // scores -> probs
    __shared__ alignas(16) float  s_pe[NHEAD][DEPTH];    // p . e
    __shared__ int    s_mask[SS];
    __shared__ float  s_red[8];

    int bi = blockIdx.x;                     // b*S + i
    int b  = bi / SS;
    int tid = threadIdx.x;
    int w = tid >> 6, l = tid & 63;

    // ---- load q row + mask row ----
    for (int c = tid; c < HH; c += 256) s_q[c] = q_ws[(size_t)bi * HH + c];
    if (tid < SS) s_mask[tid] = mask[(size_t)bi * SS + tid];
    __syncthreads();

    // ---- qek[h][d]: 4 lanes cooperate per output (coalesced Wek reads) ----
#pragma unroll 1
    for (int round = 0; round < 12; round++) {
        int lid = round * 256 + tid;         // 0..3071
        int oidx = lid >> 2;                 // 0..767 = h*64+d
        int h = oidx >> 6, d = oidx & 63;
        int c0 = (lid & 3) << 4;
        const float* wp = Wek + (size_t)d * HH + h * DHEAD + c0;
        const float* qp = s_q + h * DHEAD + c0;
        float sum = 0.f;
#pragma unroll
        for (int cc = 0; cc < 16; cc += 4) {
            float4 wv = *(const float4*)(wp + cc);
            float4 qv = *(const float4*)(qp + cc);
            sum += qv.x * wv.x + qv.y * wv.y + qv.z * wv.z + qv.w * wv.w;
        }
        sum += __shfl_xor(sum, 1, 64);
        sum += __shfl_xor(sum, 2, 64);
        if ((lid & 3) == 0) s_qek[oidx] = sum;
    }
    // qbek[h]: one thread per head
    if (tid < NHEAD) {
        const float* qp = s_q + tid * DHEAD;
        const float* bp = bek + tid * DHEAD;
        float sum = 0.f;
#pragma unroll 1
        for (int c = 0; c < DHEAD; c++) sum += qp[c] * bp[c];
        s_qbek[tid] = sum;
    }

    const float* e_row = edge + (size_t)bi * SS * DEPTH;
    const float* kT_b  = kT + (size_t)b * HH * SS;

    // ---- pass 1: scores, j-tiles of 32 (160 = 5*32) ----
    for (int jt = 0; jt < SS; jt += 32) {
        __syncthreads();   // first iter: covers qek/qbek; later: protects s_pool
        for (int idx = tid; idx < 32 * 32; idx += 256) {
            int jj = idx >> 5, dd = idx & 31;
            *(float2*)(&s_pool[jj * 66 + dd * 2]) =
                *(const float2*)(e_row + (size_t)(jt + jj) * DEPTH + dd * 2);
        }
        __syncthreads();
        for (int item = tid; item < 32 * NHEAD; item += 256) {
            int jj = item & 31, h = item >> 5;
            int j = jt + jj;
            const float* kp   = kT_b + (size_t)(h * DHEAD) * SS + j;  // + d*SS
            const float* qp   = s_q + h * DHEAD;
            const float* qekp = s_qek + h * DHEAD;
            const float* ep   = s_pool + jj * 66;
            float sum = 0.f, sum2 = 0.f;
#pragma unroll 4
            for (int d = 0; d < DHEAD; d += 4) {
                float k0 = kp[(size_t)d * SS];
                float k1 = kp[(size_t)(d + 1) * SS];
                float k2 = kp[(size_t)(d + 2) * SS];
                float k3 = kp[(size_t)(d + 3) * SS];
                float4 qv = *(const float4*)(qp + d);
                float4 qe = *(const float4*)(qekp + d);
                float2 e0 = *(const float2*)(ep + d);
                float2 e1 = *(const float2*)(ep + d + 2);
                sum  += qv.x * k0 + qv.y * k1 + qv.z * k2 + qv.w * k3;
                sum2 += qe.x * e0.x + qe.y * e0.y + qe.z * e1.x + qe.w * e1.y;
            }
            s_scores[h][j] = s_mask[j] ? (sum + sum2 + s_qbek[h]) * 0.125f
                                       : -10000.0f;
        }
    }
    __syncthreads();

    // ---- softmax per head (wave w -> heads w, w+4, w+8); S=160 = 64+64+32 ----
    for (int h = w; h < NHEAD; h += 4) {
        float v0 = s_scores[h][l];
        float v1 = s_scores[h][l + 64];
        float v2 = (l < 32) ? s_scores[h][l + 128] : -INFINITY;
        float mx = fmaxf(v0, fmaxf(v1, v2));
#pragma unroll
        for (int mm = 32; mm >= 1; mm >>= 1) mx = fmaxf(mx, __shfl_xor(mx, mm, 64));
        float e0 = expf(v0 - mx), e1 = expf(v1 - mx);
        float e2 = (l < 32) ? expf(v2 - mx) : 0.f;
        float sm = e0 + e1 + e2;
#pragma unroll
        for (int mm = 32; mm >= 1; mm >>= 1) sm += __shfl_xor(sm, mm, 64);
        float inv = 1.0f / sm;
        s_scores[h][l]      = e0 * inv;
        s_scores[h][l + 64] = e1 * inv;
        if (l < 32) s_scores[h][l + 128] = e2 * inv;
    }
    __syncthreads();

    // ---- pass 2: wave w owns heads 3w..3w+2; lane = channel ----
    // probs read as float4 broadcasts (4x fewer LDS issues); 4-j unroll keeps
    // 16 independent global loads in flight.
    {
        int h0 = w * 3;
        float av0 = 0.f, av1 = 0.f, av2 = 0.f;
        float pe0 = 0.f, pe1 = 0.f, pe2 = 0.f;
        const float* vb = v_ws + (size_t)b * SS * HH + h0 * DHEAD + l;
        const float* er = e_row + l;
        for (int j0 = 0; j0 < SS; j0 += 4) {
            float4 p0 = *(const float4*)(&s_scores[h0][j0]);
            float4 p1 = *(const float4*)(&s_scores[h0 + 1][j0]);
            float4 p2 = *(const float4*)(&s_scores[h0 + 2][j0]);
            const float* vp = vb + (size_t)j0 * HH;
            float e0 = er[(size_t)(j0 + 0) * DEPTH];
            float e1 = er[(size_t)(j0 + 1) * DEPTH];
            float e2 = er[(size_t)(j0 + 2) * DEPTH];
            float e3 = er[(size_t)(j0 + 3) * DEPTH];
            av0 += p0.x * vp[0] + p0.y * vp[HH] + p0.z * vp[2 * HH] + p0.w * vp[3 * HH];
            av1 += p1.x * vp[DHEAD] + p1.y * vp[HH + DHEAD]
                 + p1.z * vp[2 * HH + DHEAD] + p1.w * vp[3 * HH + DHEAD];
            av2 += p2.x * vp[2 * DHEAD] + p2.y * vp[HH + 2 * DHEAD]
                 + p2.z * vp[2 * HH + 2 * DHEAD] + p2.w * vp[3 * HH + 2 * DHEAD];
            pe0 += p0.x * e0 + p0.y * e1 + p0.z * e2 + p0.w * e3;
            pe1 += p1.x * e0 + p1.y * e1 + p1.z * e2 + p1.w * e3;
            pe2 += p2.x * e0 + p2.y * e1 + p2.z * e2 + p2.w * e3;
        }
        s_pe[h0][l]     = pe0;
        s_pe[h0 + 1][l] = pe1;
        s_pe[h0 + 2][l] = pe2;
        s_q[h0 * DHEAD + l]       = av0;   // s_q reused as ctx_v
        s_q[(h0 + 1) * DHEAD + l] = av1;
        s_q[(h0 + 2) * DHEAD + l] = av2;
    }
    __syncthreads();

    // ---- ctx_e = pe_h @ Wev_h + bev ; residual add (s_x aliases s_pool) ----
    float* s_x = s_pool;
    for (int mdx = tid; mdx < HH; mdx += 256) {
        int h = mdx >> 6;
        const float* pep = &s_pe[h][0];
        float sum = 0.f;
#pragma unroll 8
        for (int d = 0; d < DEPTH; d++) sum += pep[d] * Wev[(size_t)d * HH + mdx];
        float ctx = s_q[mdx] + (sum + bev[mdx]);
        s_x[mdx] = token[(size_t)bi * HH + mdx] + ctx;
    }
    __syncthreads();

    // ---- LayerNorm over H ----
    float lsum = 0.f, lsq = 0.f;
    for (int c = tid; c < HH; c += 256) {
        float x = s_x[c];
        lsum += x; lsq += x * x;
    }
#pragma unroll
    for (int mm = 32; mm >= 1; mm >>= 1) {
        lsum += __shfl_xor(lsum, mm, 64);
        lsq  += __shfl_xor(lsq,  mm, 64);
    }
    if (l == 0) { s_red[w] = lsum; s_red[4 + w] = lsq; }
    __syncthreads();
    float tsum = s_red[0] + s_red[1] + s_red[2] + s_red[3];
    float tsq  = s_red[4] + s_red[5] + s_red[6] + s_red[7];
    float mu  = tsum / HH;
    float var = tsq / HH - mu * mu;
    float rstd = rsqrtf(var + EPS_C);
    for (int c = tid; c < HH; c += 256)
        out[(size_t)bi * HH + c] = (s_x[c] - mu) * rstd * ln_g[c] + ln_b[c];
}

extern "C" void kernel_launch(void* const* d_in, const int* in_sizes, int n_in,
                              void* d_out, int out_size, void* d_ws, size_t ws_size,
                              hipStream_t stream) {
    const float* token = (const float*)d_in[0];
    const float* edge  = (const float*)d_in[1];
    const int*   mask  = (const int*)d_in[2];
    const float* Wq = (const float*)d_in[3];  const float* bq = (const float*)d_in[4];
    const float* Wk = (const float*)d_in[5];  const float* bk = (const float*)d_in[6];
    const float* Wv = (const float*)d_in[7];  const float* bv = (const float*)d_in[8];
    const float* Wek = (const float*)d_in[9];  const float* bek = (const float*)d_in[10];
    const float* Wev = (const float*)d_in[11]; const float* bev = (const float*)d_in[12];
    const float* ln_g = (const float*)d_in[13]; const float* ln_b = (const float*)d_in[14];
    float* out = (float*)d_out;

    float* q_ws  = (float*)d_ws;
    float* kT_ws = q_ws + (size_t)BS * HH;
    float* v_ws  = kT_ws + (size_t)BS * HH;

    proj_qkv<<<720, 256, 0, stream>>>(token, Wq, bq, Wk, bk, Wv, bv,
                                      q_ws, kT_ws, v_ws);
    attn_kernel<<<BS, 256, 0, stream>>>(token, edge, mask, q_ws, kT_ws, v_ws,
                                        Wek, bek, Wev, bev, ln_g, ln_b, out);
}

// Round 7
// 142.945 us; speedup vs baseline: 1.6203x; 1.6203x over previous
//
#include <hip/hip_runtime.h>
#include <hip/hip_bf16.h>
#include <math.h>

#define BB 8
#define SS 160
#define HH 768
#define DEPTH 64
#define NHEAD 12
#define DHEAD 64
#define BS (BB*SS)

constexpr float EPS_C = 1e-5f;

typedef __attribute__((ext_vector_type(8))) short bf16x8;
typedef __attribute__((ext_vector_type(4))) float f32x4;

// ---------------- cast X (f32 -> bf16, row-major) ----------------
__global__ __launch_bounds__(256) void cast_x(
    const float* __restrict__ X, __hip_bfloat16* __restrict__ Xb)
{
    int idx = blockIdx.x * 256 + threadIdx.x;      // 245760 float4 items
    float4 xin = ((const float4*)X)[idx];
    __hip_bfloat16* o = Xb + (size_t)idx * 4;
    o[0] = __float2bfloat16(xin.x); o[1] = __float2bfloat16(xin.y);
    o[2] = __float2bfloat16(xin.z); o[3] = __float2bfloat16(xin.w);
}

// ---------------- transpose+cast W[k][n] f32 -> WT[n][k] bf16 ----------------
__global__ __launch_bounds__(256) void transpose_cast_w(
    const float* __restrict__ Wq, const float* __restrict__ Wk,
    const float* __restrict__ Wv, __hip_bfloat16* __restrict__ WT)
{
    __shared__ float t[32][33];
    const float* W = (blockIdx.z == 0) ? Wq : (blockIdx.z == 1) ? Wk : Wv;
    __hip_bfloat16* o = WT + (size_t)blockIdx.z * HH * HH;
    int kt = blockIdx.x * 32, nt = blockIdx.y * 32;
    int tx = threadIdx.x & 31, ty = threadIdx.x >> 5;   // ty 0..7
#pragma unroll
    for (int r = 0; r < 32; r += 8)
        t[ty + r][tx] = W[(size_t)(kt + ty + r) * HH + nt + tx];
    __syncthreads();
#pragma unroll
    for (int r = 0; r < 32; r += 8)
        o[(size_t)(nt + ty + r) * HH + kt + tx] = __float2bfloat16(t[tx][ty + r]);
}

// ---------------- MFMA GEMM: {q,k,v} = X @ W + b (bf16 in, f32 acc) ----------
// Tile 128(M)x64(N), K-step 32, 4 waves in 2x2 grid (each wave 64x32).
// LDS layout [kchunk(4)][row][8 bf16]: frag reads are consecutive 16B (no
// bank conflicts); staging threads: chunk = wave id, row = lane (conflict-free
// writes; global gather strided but L1/L2 absorbs).
// mfma_f32_16x16x32_bf16 layouts: A lane&15=m-row, k=(lane>>4)*8+j;
// B lane&15=n-col, k=(lane>>4)*8+j; C col=lane&15, row=(lane>>4)*4+reg [m89].
__global__ __launch_bounds__(256) void gemm_qkv(
    const __hip_bfloat16* __restrict__ Xb, const __hip_bfloat16* __restrict__ WT,
    const float* __restrict__ bq, const float* __restrict__ bk,
    const float* __restrict__ bv,
    __hip_bfloat16* __restrict__ qb, __hip_bfloat16* __restrict__ kTb,
    __hip_bfloat16* __restrict__ vb)
{
    __shared__ int4 sA[4][128];   // 8 KB
    __shared__ int4 sB[4][64];    // 4 KB
    int m0 = blockIdx.x * 128, n0 = blockIdx.y * 64, mat = blockIdx.z;
    const short* X = (const short*)Xb;
    const short* W = (const short*)WT + (size_t)mat * HH * HH;
    const float* bias = (mat == 0) ? bq : (mat == 1) ? bk : bv;
    int tid = threadIdx.x, w = tid >> 6, l = tid & 63;
    int wm = (w >> 1) * 64, wn = (w & 1) * 32;
    int khalf = l >> 4, lc = l & 15;

    f32x4 acc[4][2];
#pragma unroll
    for (int i = 0; i < 4; i++)
#pragma unroll
        for (int j = 0; j < 2; j++) acc[i][j] = (f32x4){0.f, 0.f, 0.f, 0.f};

    for (int k0 = 0; k0 < HH; k0 += 32) {
        __syncthreads();
        // stage: wave w loads k-chunk w; lane = row
        sA[w][l]      = *(const int4*)(X + (size_t)(m0 + l) * HH + k0 + w * 8);
        sA[w][l + 64] = *(const int4*)(X + (size_t)(m0 + l + 64) * HH + k0 + w * 8);
        sB[w][l]      = *(const int4*)(W + (size_t)(n0 + l) * HH + k0 + w * 8);
        __syncthreads();
        bf16x8 b0 = *(const bf16x8*)&sB[khalf][wn + lc];
        bf16x8 b1 = *(const bf16x8*)&sB[khalf][wn + 16 + lc];
#pragma unroll
        for (int mi = 0; mi < 4; mi++) {
            bf16x8 a = *(const bf16x8*)&sA[khalf][wm + mi * 16 + lc];
            acc[mi][0] = __builtin_amdgcn_mfma_f32_16x16x32_bf16(a, b0, acc[mi][0], 0, 0, 0);
            acc[mi][1] = __builtin_amdgcn_mfma_f32_16x16x32_bf16(a, b1, acc[mi][1], 0, 0, 0);
        }
    }

    int rg = (l >> 4) * 4;
#pragma unroll
    for (int ni = 0; ni < 2; ni++) {
        int gcol = n0 + wn + ni * 16 + lc;
        float bv_ = bias[gcol];
#pragma unroll
        for (int mi = 0; mi < 4; mi++) {
            int grow = m0 + wm + mi * 16 + rg;     // 4 consecutive rows
            f32x4 a = acc[mi][ni];
            if (mat == 1) {
                // kT[b][ch][j]: 4 consecutive j (rg mult of 4, never crosses b)
                int bb = grow / SS; int i0 = grow - bb * SS;
                __hip_bfloat16* dst = kTb + ((size_t)bb * HH + gcol) * SS + i0;
                dst[0] = __float2bfloat16(a.x + bv_);
                dst[1] = __float2bfloat16(a.y + bv_);
                dst[2] = __float2bfloat16(a.z + bv_);
                dst[3] = __float2bfloat16(a.w + bv_);
            } else {
                __hip_bfloat16* o = ((mat == 0) ? qb : vb) + (size_t)grow * HH + gcol;
                o[0]      = __float2bfloat16(a.x + bv_);
                o[HH]     = __float2bfloat16(a.y + bv_);
                o[2 * HH] = __float2bfloat16(a.z + bv_);
                o[3 * HH] = __float2bfloat16(a.w + bv_);
            }
        }
    }
}

// ---------------- Fused attention + edge terms + LayerNorm ----------------
// R5-validated structure; q/kT/v now bf16 (half the L2 traffic).
__global__ __launch_bounds__(256) void attn_kernel(
    const float* __restrict__ token, const float* __restrict__ edge,
    const int* __restrict__ mask,
    const __hip_bfloat16* __restrict__ q_ws, const __hip_bfloat16* __restrict__ kT,
    const __hip_bfloat16* __restrict__ v_ws,
    const float* __restrict__ Wek, const float* __restrict__ bek,
    const float* __restrict__ Wev, const float* __restrict__ bev,
    const float* __restrict__ ln_g, const float* __restrict__ ln_b,
    float* __restrict__ out)
{
    __shared__ float  s_q[HH];               // q row; reused as ctx_v after pass2
    __shared__ float  s_qek[NHEAD * DEPTH];  // [h][d] = Wek_h^T q_h
    __shared__ float  s_qbek[NHEAD];
    __shared__ float  s_pool[32 * 66];       // e tile [32][66] in pass1; s_x later
    __shared__ float  s_scores[NHEAD][SS];   // scores -> probs
    __shared__ float  s_pe[NHEAD][DEPTH];    // p . e
    __shared__ int    s_mask[SS];
    __shared__ float  s_red[8];

    int bi = blockIdx.x;                     // b*S + i
    int b  = bi / SS;
    int tid = threadIdx.x;
    int w = tid >> 6, l = tid & 63;

    // ---- load q row + mask row ----
    for (int c = tid; c < HH; c += 256)
        s_q[c] = __bfloat162float(q_ws[(size_t)bi * HH + c]);
    if (tid < SS) s_mask[tid] = mask[(size_t)bi * SS + tid];
    __syncthreads();

    // ---- qek[h][d]: 4 lanes cooperate per output (coalesced Wek reads) ----
#pragma unroll
    for (int round = 0; round < 12; round++) {
        int lid = round * 256 + tid;         // 0..3071
        int oidx = lid >> 2;                 // 0..767 = h*64+d
        int h = oidx >> 6, d = oidx & 63;
        int c0 = (lid & 3) << 4;
        const float* wp = Wek + (size_t)d * HH + h * DHEAD + c0;
        const float* qp = s_q + h * DHEAD + c0;
        float sum = 0.f;
#pragma unroll
        for (int cc = 0; cc < 16; cc += 4) {
            float4 wv = *(const float4*)(wp + cc);
            float4 qv = *(const float4*)(qp + cc);
            sum += qv.x * wv.x + qv.y * wv.y + qv.z * wv.z + qv.w * wv.w;
        }
        sum += __shfl_xor(sum, 1, 64);
        sum += __shfl_xor(sum, 2, 64);
        if ((lid & 3) == 0) s_qek[oidx] = sum;
    }
    // qbek[h]: one thread per head
    if (tid < NHEAD) {
        const float* qp = s_q + tid * DHEAD;
        const float* bp = bek + tid * DHEAD;
        float sum = 0.f;
#pragma unroll
        for (int c = 0; c < DHEAD; c++) sum += qp[c] * bp[c];
        s_qbek[tid] = sum;
    }

    const float* e_row = edge + (size_t)bi * SS * DEPTH;
    const __hip_bfloat16* kT_b = kT + (size_t)b * HH * SS;

    // ---- pass 1: scores, j-tiles of 32 (160 = 5*32) ----
    for (int jt = 0; jt < SS; jt += 32) {
        __syncthreads();   // first iter: covers qek/qbek; later: protects s_pool
        for (int idx = tid; idx < 32 * 32; idx += 256) {
            int jj = idx >> 5, dd = idx & 31;
            *(float2*)(&s_pool[jj * 66 + dd * 2]) =
                *(const float2*)(e_row + (size_t)(jt + jj) * DEPTH + dd * 2);
        }
        __syncthreads();
        for (int item = tid; item < 32 * NHEAD; item += 256) {
            int jj = item & 31, h = item >> 5;
            int j = jt + jj;
            const __hip_bfloat16* kp = kT_b + (size_t)(h * DHEAD) * SS + j; // +d*SS
            const float* qp   = s_q + h * DHEAD;
            const float* qekp = s_qek + h * DHEAD;
            const float* ep   = s_pool + jj * 66;
            float sum = 0.f, sum2 = 0.f;
#pragma unroll
            for (int d = 0; d < DHEAD; d += 4) {
                float k0 = __bfloat162float(kp[(size_t)d * SS]);
                float k1 = __bfloat162float(kp[(size_t)(d + 1) * SS]);
                float k2 = __bfloat162float(kp[(size_t)(d + 2) * SS]);
                float k3 = __bfloat162float(kp[(size_t)(d + 3) * SS]);
                float4 qv = *(const float4*)(qp + d);
                float4 qe = *(const float4*)(qekp + d);
                float2 e0 = *(const float2*)(ep + d);
                float2 e1 = *(const float2*)(ep + d + 2);
                sum  += qv.x * k0 + qv.y * k1 + qv.z * k2 + qv.w * k3;
                sum2 += qe.x * e0.x + qe.y * e0.y + qe.z * e1.x + qe.w * e1.y;
            }
            s_scores[h][j] = s_mask[j] ? (sum + sum2 + s_qbek[h]) * 0.125f
                                       : -10000.0f;
        }
    }
    __syncthreads();

    // ---- softmax per head (wave w -> heads w, w+4, w+8); S=160 = 64+64+32 ----
    for (int h = w; h < NHEAD; h += 4) {
        float v0 = s_scores[h][l];
        float v1 = s_scores[h][l + 64];
        float v2 = (l < 32) ? s_scores[h][l + 128] : -INFINITY;
        float mx = fmaxf(v0, fmaxf(v1, v2));
#pragma unroll
        for (int mm = 32; mm >= 1; mm >>= 1) mx = fmaxf(mx, __shfl_xor(mx, mm, 64));
        float e0 = expf(v0 - mx), e1 = expf(v1 - mx);
        float e2 = (l < 32) ? expf(v2 - mx) : 0.f;
        float sm = e0 + e1 + e2;
#pragma unroll
        for (int mm = 32; mm >= 1; mm >>= 1) sm += __shfl_xor(sm, mm, 64);
        float inv = 1.0f / sm;
        s_scores[h][l]      = e0 * inv;
        s_scores[h][l + 64] = e1 * inv;
        if (l < 32) s_scores[h][l + 128] = e2 * inv;
    }
    __syncthreads();

    // ---- pass 2: wave w owns heads 3w..3w+2; lane = channel; dense ----
    {
        int h0 = w * 3;
        float av0 = 0.f, av1 = 0.f, av2 = 0.f;
        float pe0 = 0.f, pe1 = 0.f, pe2 = 0.f;
        const __hip_bfloat16* vbp = v_ws + (size_t)b * SS * HH + h0 * DHEAD + l;
        const float* er = e_row + l;
        const float* p0r = &s_scores[h0][0];
        const float* p1r = &s_scores[h0 + 1][0];
        const float* p2r = &s_scores[h0 + 2][0];
#pragma unroll 4
        for (int j = 0; j < SS; j++) {
            float p0 = p0r[j], p1 = p1r[j], p2 = p2r[j];
            const __hip_bfloat16* vp = vbp + (size_t)j * HH;
            av0 += p0 * __bfloat162float(vp[0]);
            av1 += p1 * __bfloat162float(vp[DHEAD]);
            av2 += p2 * __bfloat162float(vp[2 * DHEAD]);
            float ev = er[(size_t)j * DEPTH];
            pe0 += p0 * ev; pe1 += p1 * ev; pe2 += p2 * ev;
        }
        s_pe[h0][l]     = pe0;
        s_pe[h0 + 1][l] = pe1;
        s_pe[h0 + 2][l] = pe2;
        s_q[h0 * DHEAD + l]       = av0;   // s_q reused as ctx_v
        s_q[(h0 + 1) * DHEAD + l] = av1;
        s_q[(h0 + 2) * DHEAD + l] = av2;
    }
    __syncthreads();

    // ---- ctx_e = pe_h @ Wev_h + bev ; residual add (s_x aliases s_pool) ----
    float* s_x = s_pool;
    for (int mdx = tid; mdx < HH; mdx += 256) {
        int h = mdx >> 6;
        const float* pep = &s_pe[h][0];
        float sum = 0.f;
#pragma unroll
        for (int d = 0; d < DEPTH; d++) sum += pep[d] * Wev[(size_t)d * HH + mdx];
        float ctx = s_q[mdx] + (sum + bev[mdx]);
        s_x[mdx] = token[(size_t)bi * HH + mdx] + ctx;
    }
    __syncthreads();

    // ---- LayerNorm over H ----
    float lsum = 0.f, lsq = 0.f;
    for (int c = tid; c < HH; c += 256) {
        float x = s_x[c];
        lsum += x; lsq += x * x;
    }
#pragma unroll
    for (int mm = 32; mm >= 1; mm >>= 1) {
        lsum += __shfl_xor(lsum, mm, 64);
        lsq  += __shfl_xor(lsq,  mm, 64);
    }
    if (l == 0) { s_red[w] = lsum; s_red[4 + w] = lsq; }
    __syncthreads();
    float tsum = s_red[0] + s_red[1] + s_red[2] + s_red[3];
    float tsq  = s_red[4] + s_red[5] + s_red[6] + s_red[7];
    float mu  = tsum / HH;
    float var = tsq / HH - mu * mu;
    float rstd = rsqrtf(var + EPS_C);
    for (int c = tid; c < HH; c += 256)
        out[(size_t)bi * HH + c] = (s_x[c] - mu) * rstd * ln_g[c] + ln_b[c];
}

extern "C" void kernel_launch(void* const* d_in, const int* in_sizes, int n_in,
                              void* d_out, int out_size, void* d_ws, size_t ws_size,
                              hipStream_t stream) {
    const float* token = (const float*)d_in[0];
    const float* edge  = (const float*)d_in[1];
    const int*   mask  = (const int*)d_in[2];
    const float* Wq = (const float*)d_in[3];  const float* bq = (const float*)d_in[4];
    const float* Wk = (const float*)d_in[5];  const float* bk = (const float*)d_in[6];
    const float* Wv = (const float*)d_in[7];  const float* bv = (const float*)d_in[8];
    const float* Wek = (const float*)d_in[9];  const float* bek = (const float*)d_in[10];
    const float* Wev = (const float*)d_in[11]; const float* bev = (const float*)d_in[12];
    const float* ln_g = (const float*)d_in[13]; const float* ln_b = (const float*)d_in[14];
    float* out = (float*)d_out;

    // ws layout (bf16): q, kT, v, Xb [each 1280*768], WT [3*768*768]  = 11.4 MB
    __hip_bfloat16* qb  = (__hip_bfloat16*)d_ws;
    __hip_bfloat16* kTb = qb  + (size_t)BS * HH;
    __hip_bfloat16* vb  = kTb + (size_t)BS * HH;
    __hip_bfloat16* Xb  = vb  + (size_t)BS * HH;
    __hip_bfloat16* WT  = Xb  + (size_t)BS * HH;

    cast_x<<<(BS * HH / 4) / 256, 256, 0, stream>>>(token, Xb);
    transpose_cast_w<<<dim3(24, 24, 3), 256, 0, stream>>>(Wq, Wk, Wv, WT);
    gemm_qkv<<<dim3(BS / 128, HH / 64, 3), 256, 0, stream>>>(
        Xb, WT, bq, bk, bv, qb, kTb, vb);
    attn_kernel<<<BS, 256, 0, stream>>>(token, edge, mask, qb, kTb, vb,
                                        Wek, bek, Wev, bev, ln_g, ln_b, out);
}

// Round 8
// 135.841 us; speedup vs baseline: 1.7050x; 1.0523x over previous
//
#include <hip/hip_runtime.h>
#include <hip/hip_bf16.h>
#include <math.h>

#define BB 8
#define SS 160
#define HH 768
#define DEPTH 64
#define NHEAD 12
#define DHEAD 64
#define BS (BB*SS)

constexpr float EPS_C = 1e-5f;

typedef __attribute__((ext_vector_type(8))) short bf16x8;
typedef __attribute__((ext_vector_type(4))) float f32x4;

// ---------------- cast X (f32 -> bf16, row-major) ----------------
__global__ __launch_bounds__(256) void cast_x(
    const float* __restrict__ X, __hip_bfloat16* __restrict__ Xb)
{
    int idx = blockIdx.x * 256 + threadIdx.x;      // 245760 float4 items
    float4 xin = ((const float4*)X)[idx];
    __hip_bfloat16* o = Xb + (size_t)idx * 4;
    o[0] = __float2bfloat16(xin.x); o[1] = __float2bfloat16(xin.y);
    o[2] = __float2bfloat16(xin.z); o[3] = __float2bfloat16(xin.w);
}

// ---------------- transpose+cast W[k][n] f32 -> WT[n][k] bf16 ----------------
__global__ __launch_bounds__(256) void transpose_cast_w(
    const float* __restrict__ Wq, const float* __restrict__ Wk,
    const float* __restrict__ Wv, __hip_bfloat16* __restrict__ WT)
{
    __shared__ float t[32][33];
    const float* W = (blockIdx.z == 0) ? Wq : (blockIdx.z == 1) ? Wk : Wv;
    __hip_bfloat16* o = WT + (size_t)blockIdx.z * HH * HH;
    int kt = blockIdx.x * 32, nt = blockIdx.y * 32;
    int tx = threadIdx.x & 31, ty = threadIdx.x >> 5;   // ty 0..7
#pragma unroll
    for (int r = 0; r < 32; r += 8)
        t[ty + r][tx] = W[(size_t)(kt + ty + r) * HH + nt + tx];
    __syncthreads();
#pragma unroll
    for (int r = 0; r < 32; r += 8)
        o[(size_t)(nt + ty + r) * HH + kt + tx] = __float2bfloat16(t[tx][ty + r]);
}

// ---------------- MFMA GEMM: {q,k,v} = X @ W + b (bf16 in, f32 acc) ----------
// Tile 128(M)x64(N), K-step 32, 4 waves 2x2. All outputs row-major bf16.
__global__ __launch_bounds__(256) void gemm_qkv(
    const __hip_bfloat16* __restrict__ Xb, const __hip_bfloat16* __restrict__ WT,
    const float* __restrict__ bq, const float* __restrict__ bk,
    const float* __restrict__ bv,
    __hip_bfloat16* __restrict__ qb, __hip_bfloat16* __restrict__ kb,
    __hip_bfloat16* __restrict__ vb)
{
    __shared__ int4 sA[4][128];   // 8 KB
    __shared__ int4 sB[4][64];    // 4 KB
    int m0 = blockIdx.x * 128, n0 = blockIdx.y * 64, mat = blockIdx.z;
    const short* X = (const short*)Xb;
    const short* W = (const short*)WT + (size_t)mat * HH * HH;
    const float* bias = (mat == 0) ? bq : (mat == 1) ? bk : bv;
    int tid = threadIdx.x, w = tid >> 6, l = tid & 63;
    int wm = (w >> 1) * 64, wn = (w & 1) * 32;
    int khalf = l >> 4, lc = l & 15;

    f32x4 acc[4][2];
#pragma unroll
    for (int i = 0; i < 4; i++)
#pragma unroll
        for (int j = 0; j < 2; j++) acc[i][j] = (f32x4){0.f, 0.f, 0.f, 0.f};

    for (int k0 = 0; k0 < HH; k0 += 32) {
        __syncthreads();
        sA[w][l]      = *(const int4*)(X + (size_t)(m0 + l) * HH + k0 + w * 8);
        sA[w][l + 64] = *(const int4*)(X + (size_t)(m0 + l + 64) * HH + k0 + w * 8);
        sB[w][l]      = *(const int4*)(W + (size_t)(n0 + l) * HH + k0 + w * 8);
        __syncthreads();
        bf16x8 b0 = *(const bf16x8*)&sB[khalf][wn + lc];
        bf16x8 b1 = *(const bf16x8*)&sB[khalf][wn + 16 + lc];
#pragma unroll
        for (int mi = 0; mi < 4; mi++) {
            bf16x8 a = *(const bf16x8*)&sA[khalf][wm + mi * 16 + lc];
            acc[mi][0] = __builtin_amdgcn_mfma_f32_16x16x32_bf16(a, b0, acc[mi][0], 0, 0, 0);
            acc[mi][1] = __builtin_amdgcn_mfma_f32_16x16x32_bf16(a, b1, acc[mi][1], 0, 0, 0);
        }
    }

    int rg = (l >> 4) * 4;
    __hip_bfloat16* outm = (mat == 0) ? qb : (mat == 1) ? kb : vb;
#pragma unroll
    for (int ni = 0; ni < 2; ni++) {
        int gcol = n0 + wn + ni * 16 + lc;
        float bv_ = bias[gcol];
#pragma unroll
        for (int mi = 0; mi < 4; mi++) {
            int grow = m0 + wm + mi * 16 + rg;
            f32x4 a = acc[mi][ni];
            __hip_bfloat16* o = outm + (size_t)grow * HH + gcol;
            o[0]      = __float2bfloat16(a.x + bv_);
            o[HH]     = __float2bfloat16(a.y + bv_);
            o[2 * HH] = __float2bfloat16(a.z + bv_);
            o[3 * HH] = __float2bfloat16(a.w + bv_);
        }
    }
}

// ---------------- MFMA scores: S[b][h] = (Q_h K_h^T) * 0.125, f16 out -------
// One block per (b,h); K=64 staged whole; 4 waves 2x2, each 80x80.
__global__ __launch_bounds__(256) void scores_gemm(
    const __hip_bfloat16* __restrict__ qb, const __hip_bfloat16* __restrict__ kb,
    _Float16* __restrict__ sc)
{
    __shared__ int4 sQ[8][160];   // 20.5 KB
    __shared__ int4 sK[8][160];
    int h = blockIdx.x, b = blockIdx.y;
    const short* Q = (const short*)qb + (size_t)b * SS * HH + h * DHEAD;
    const short* K = (const short*)kb + (size_t)b * SS * HH + h * DHEAD;
    int tid = threadIdx.x, w = tid >> 6, l = tid & 63;

    for (int idx = tid; idx < SS * 8; idx += 256) {
        int row = idx >> 3, ch = idx & 7;
        sQ[ch][row] = *(const int4*)(Q + (size_t)row * HH + ch * 8);
        sK[ch][row] = *(const int4*)(K + (size_t)row * HH + ch * 8);
    }
    __syncthreads();

    int wm = (w >> 1) * 80, wn = (w & 1) * 80;
    int khalf = l >> 4, lc = l & 15;
    f32x4 acc[5][5];
#pragma unroll
    for (int i = 0; i < 5; i++)
#pragma unroll
        for (int j = 0; j < 5; j++) acc[i][j] = (f32x4){0.f, 0.f, 0.f, 0.f};

#pragma unroll
    for (int s = 0; s < 2; s++) {
        int c = s * 4 + khalf;
        bf16x8 bf[5];
#pragma unroll
        for (int ni = 0; ni < 5; ni++)
            bf[ni] = *(const bf16x8*)&sK[c][wn + ni * 16 + lc];
#pragma unroll
        for (int mi = 0; mi < 5; mi++) {
            bf16x8 a = *(const bf16x8*)&sQ[c][wm + mi * 16 + lc];
#pragma unroll
            for (int ni = 0; ni < 5; ni++)
                acc[mi][ni] = __builtin_amdgcn_mfma_f32_16x16x32_bf16(a, bf[ni], acc[mi][ni], 0, 0, 0);
        }
    }

    int rg = (l >> 4) * 4;
    _Float16* base = sc + (size_t)(b * NHEAD + h) * SS * SS;
#pragma unroll
    for (int mi = 0; mi < 5; mi++) {
        int i0 = wm + mi * 16 + rg;
#pragma unroll
        for (int ni = 0; ni < 5; ni++) {
            int j = wn + ni * 16 + lc;
            f32x4 a = acc[mi][ni];
            base[(size_t)(i0 + 0) * SS + j] = (_Float16)(a.x * 0.125f);
            base[(size_t)(i0 + 1) * SS + j] = (_Float16)(a.y * 0.125f);
            base[(size_t)(i0 + 2) * SS + j] = (_Float16)(a.z * 0.125f);
            base[(size_t)(i0 + 3) * SS + j] = (_Float16)(a.w * 0.125f);
        }
    }
}

// ---------------- Fused attention epilogue + LayerNorm ----------------
// One block per (b,i). qk scores read from ws (MFMA-computed); pass-1 only
// adds the e.qek term. Rest identical to the validated R5/R7 structure.
__global__ __launch_bounds__(256) void attn_kernel(
    const float* __restrict__ token, const float* __restrict__ edge,
    const int* __restrict__ mask,
    const __hip_bfloat16* __restrict__ q_ws, const _Float16* __restrict__ sc,
    const __hip_bfloat16* __restrict__ v_ws,
    const float* __restrict__ Wek, const float* __restrict__ bek,
    const float* __restrict__ Wev, const float* __restrict__ bev,
    const float* __restrict__ ln_g, const float* __restrict__ ln_b,
    float* __restrict__ out)
{
    __shared__ float  s_q[HH];               // q row; reused as ctx_v after pass2
    __shared__ float  s_qek[NHEAD * DEPTH];  // [h][d] = Wek_h^T q_h
    __shared__ float  s_qbek[NHEAD];
    __shared__ float  s_pool[32 * 66];       // e tile [32][66] pass1; s_x later
    __shared__ float  s_scores[NHEAD][SS];   // scores -> probs
    __shared__ float  s_pe[NHEAD][DEPTH];    // p . e
    __shared__ int    s_mask[SS];
    __shared__ float  s_red[8];

    int bi = blockIdx.x;                     // b*S + i
    int b  = bi / SS;
    int i  = bi - b * SS;
    int tid = threadIdx.x;
    int w = tid >> 6, l = tid & 63;

    // ---- load q row + mask row ----
    for (int c = tid; c < HH; c += 256)
        s_q[c] = __bfloat162float(q_ws[(size_t)bi * HH + c]);
    if (tid < SS) s_mask[tid] = mask[(size_t)bi * SS + tid];
    __syncthreads();

    // ---- qek[h][d]: 4 lanes cooperate per output (coalesced Wek reads) ----
#pragma unroll
    for (int round = 0; round < 12; round++) {
        int lid = round * 256 + tid;         // 0..3071
        int oidx = lid >> 2;                 // 0..767 = h*64+d
        int h = oidx >> 6, d = oidx & 63;
        int c0 = (lid & 3) << 4;
        const float* wp = Wek + (size_t)d * HH + h * DHEAD + c0;
        const float* qp = s_q + h * DHEAD + c0;
        float sum = 0.f;
#pragma unroll
        for (int cc = 0; cc < 16; cc += 4) {
            float4 wv = *(const float4*)(wp + cc);
            float4 qv = *(const float4*)(qp + cc);
            sum += qv.x * wv.x + qv.y * wv.y + qv.z * wv.z + qv.w * wv.w;
        }
        sum += __shfl_xor(sum, 1, 64);
        sum += __shfl_xor(sum, 2, 64);
        if ((lid & 3) == 0) s_qek[oidx] = sum;
    }
    // qbek[h]: one thread per head
    if (tid < NHEAD) {
        const float* qp = s_q + tid * DHEAD;
        const float* bp = bek + tid * DHEAD;
        float sum = 0.f;
#pragma unroll
        for (int c = 0; c < DHEAD; c++) sum += qp[c] * bp[c];
        s_qbek[tid] = sum;
    }

    const float* e_row = edge + (size_t)bi * SS * DEPTH;
    const _Float16* scp = sc + (size_t)b * NHEAD * SS * SS + (size_t)i * SS;

    // ---- pass 1: scores = qk(ws) + e.qek, j-tiles of 32 ----
    for (int jt = 0; jt < SS; jt += 32) {
        __syncthreads();   // first iter: covers qek/qbek; later: protects s_pool
        for (int idx = tid; idx < 32 * 32; idx += 256) {
            int jj = idx >> 5, dd = idx & 31;
            *(float2*)(&s_pool[jj * 66 + dd * 2]) =
                *(const float2*)(e_row + (size_t)(jt + jj) * DEPTH + dd * 2);
        }
        __syncthreads();
        for (int item = tid; item < 32 * NHEAD; item += 256) {
            int jj = item & 31, h = item >> 5;
            int j = jt + jj;
            float qk = (float)scp[(size_t)h * (SS * SS) + j];
            const float* qekp = s_qek + h * DHEAD;
            const float* ep   = s_pool + jj * 66;
            float sum2 = 0.f;
#pragma unroll
            for (int d = 0; d < DHEAD; d += 4) {
                float4 qe = *(const float4*)(qekp + d);
                float2 e0 = *(const float2*)(ep + d);
                float2 e1 = *(const float2*)(ep + d + 2);
                sum2 += qe.x * e0.x + qe.y * e0.y + qe.z * e1.x + qe.w * e1.y;
            }
            s_scores[h][j] = s_mask[j] ? qk + (sum2 + s_qbek[h]) * 0.125f
                                       : -10000.0f;
        }
    }
    __syncthreads();

    // ---- softmax per head (wave w -> heads w, w+4, w+8); S=160 = 64+64+32 ----
    for (int h = w; h < NHEAD; h += 4) {
        float v0 = s_scores[h][l];
        float v1 = s_scores[h][l + 64];
        float v2 = (l < 32) ? s_scores[h][l + 128] : -INFINITY;
        float mx = fmaxf(v0, fmaxf(v1, v2));
#pragma unroll
        for (int mm = 32; mm >= 1; mm >>= 1) mx = fmaxf(mx, __shfl_xor(mx, mm, 64));
        float e0 = expf(v0 - mx), e1 = expf(v1 - mx);
        float e2 = (l < 32) ? expf(v2 - mx) : 0.f;
        float sm = e0 + e1 + e2;
#pragma unroll
        for (int mm = 32; mm >= 1; mm >>= 1) sm += __shfl_xor(sm, mm, 64);
        float inv = 1.0f / sm;
        s_scores[h][l]      = e0 * inv;
        s_scores[h][l + 64] = e1 * inv;
        if (l < 32) s_scores[h][l + 128] = e2 * inv;
    }
    __syncthreads();

    // ---- pass 2: wave w owns heads 3w..3w+2; lane = channel; dense ----
    {
        int h0 = w * 3;
        float av0 = 0.f, av1 = 0.f, av2 = 0.f;
        float pe0 = 0.f, pe1 = 0.f, pe2 = 0.f;
        const __hip_bfloat16* vbp = v_ws + (size_t)b * SS * HH + h0 * DHEAD + l;
        const float* er = e_row + l;
        const float* p0r = &s_scores[h0][0];
        const float* p1r = &s_scores[h0 + 1][0];
        const float* p2r = &s_scores[h0 + 2][0];
#pragma unroll 4
        for (int j = 0; j < SS; j++) {
            float p0 = p0r[j], p1 = p1r[j], p2 = p2r[j];
            const __hip_bfloat16* vp = vbp + (size_t)j * HH;
            av0 += p0 * __bfloat162float(vp[0]);
            av1 += p1 * __bfloat162float(vp[DHEAD]);
            av2 += p2 * __bfloat162float(vp[2 * DHEAD]);
            float ev = er[(size_t)j * DEPTH];
            pe0 += p0 * ev; pe1 += p1 * ev; pe2 += p2 * ev;
        }
        s_pe[h0][l]     = pe0;
        s_pe[h0 + 1][l] = pe1;
        s_pe[h0 + 2][l] = pe2;
        s_q[h0 * DHEAD + l]       = av0;   // s_q reused as ctx_v
        s_q[(h0 + 1) * DHEAD + l] = av1;
        s_q[(h0 + 2) * DHEAD + l] = av2;
    }
    __syncthreads();

    // ---- ctx_e = pe_h @ Wev_h + bev ; residual add (s_x aliases s_pool) ----
    float* s_x = s_pool;
    for (int mdx = tid; mdx < HH; mdx += 256) {
        int h = mdx >> 6;
        const float* pep = &s_pe[h][0];
        float sum = 0.f;
#pragma unroll
        for (int d = 0; d < DEPTH; d++) sum += pep[d] * Wev[(size_t)d * HH + mdx];
        float ctx = s_q[mdx] + (sum + bev[mdx]);
        s_x[mdx] = token[(size_t)bi * HH + mdx] + ctx;
    }
    __syncthreads();

    // ---- LayerNorm over H ----
    float lsum = 0.f, lsq = 0.f;
    for (int c = tid; c < HH; c += 256) {
        float x = s_x[c];
        lsum += x; lsq += x * x;
    }
#pragma unroll
    for (int mm = 32; mm >= 1; mm >>= 1) {
        lsum += __shfl_xor(lsum, mm, 64);
        lsq  += __shfl_xor(lsq,  mm, 64);
    }
    if (l == 0) { s_red[w] = lsum; s_red[4 + w] = lsq; }
    __syncthreads();
    float tsum = s_red[0] + s_red[1] + s_red[2] + s_red[3];
    float tsq  = s_red[4] + s_red[5] + s_red[6] + s_red[7];
    float mu  = tsum / HH;
    float var = tsq / HH - mu * mu;
    float rstd = rsqrtf(var + EPS_C);
    for (int c = tid; c < HH; c += 256)
        out[(size_t)bi * HH + c] = (s_x[c] - mu) * rstd * ln_g[c] + ln_b[c];
}

extern "C" void kernel_launch(void* const* d_in, const int* in_sizes, int n_in,
                              void* d_out, int out_size, void* d_ws, size_t ws_size,
                              hipStream_t stream) {
    const float* token = (const float*)d_in[0];
    const float* edge  = (const float*)d_in[1];
    const int*   mask  = (const int*)d_in[2];
    const float* Wq = (const float*)d_in[3];  const float* bq = (const float*)d_in[4];
    const float* Wk = (const float*)d_in[5];  const float* bk = (const float*)d_in[6];
    const float* Wv = (const float*)d_in[7];  const float* bv = (const float*)d_in[8];
    const float* Wek = (const float*)d_in[9];  const float* bek = (const float*)d_in[10];
    const float* Wev = (const float*)d_in[11]; const float* bev = (const float*)d_in[12];
    const float* ln_g = (const float*)d_in[13]; const float* ln_b = (const float*)d_in[14];
    float* out = (float*)d_out;

    // ws layout (10.9 MB total, proven budget):
    // [qb][kb][vb][Xb][WT]; scores f16 (4.92 MB) aliases [Xb..WT] (5.25 MB)
    // after gemm_qkv is done reading them (same-stream ordering).
    __hip_bfloat16* qb = (__hip_bfloat16*)d_ws;
    __hip_bfloat16* kb = qb + (size_t)BS * HH;
    __hip_bfloat16* vb = kb + (size_t)BS * HH;
    __hip_bfloat16* Xb = vb + (size_t)BS * HH;
    __hip_bfloat16* WT = Xb + (size_t)BS * HH;
    _Float16*       sc = (_Float16*)Xb;

    cast_x<<<(BS * HH / 4) / 256, 256, 0, stream>>>(token, Xb);
    transpose_cast_w<<<dim3(24, 24, 3), 256, 0, stream>>>(Wq, Wk, Wv, WT);
    gemm_qkv<<<dim3(BS / 128, HH / 64, 3), 256, 0, stream>>>(
        Xb, WT, bq, bk, bv, qb, kb, vb);
    scores_gemm<<<dim3(NHEAD, BB), 256, 0, stream>>>(qb, kb, sc);
    attn_kernel<<<BS, 256, 0, stream>>>(token, edge, mask, qb, sc, vb,
                                        Wek, bek, Wev, bev, ln_g, ln_b, out);
}

// Round 9
// 108.896 us; speedup vs baseline: 2.1269x; 1.2474x over previous
//
#include <hip/hip_runtime.h>
#include <hip/hip_bf16.h>
#include <math.h>

#define BB 8
#define SS 160
#define HH 768
#define DEPTH 64
#define NHEAD 12
#define DHEAD 64
#define BS (BB*SS)

constexpr float EPS_C = 1e-5f;

typedef __attribute__((ext_vector_type(8))) short bf16x8;
typedef __attribute__((ext_vector_type(4))) float f32x4;

__device__ inline short f2bs(float x) {
    union { __hip_bfloat16 b; short s; } u;
    u.b = __float2bfloat16(x);
    return u.s;
}

// ---------------- cast X (f32 -> bf16, row-major) ----------------
__global__ __launch_bounds__(256) void cast_x(
    const float* __restrict__ X, __hip_bfloat16* __restrict__ Xb)
{
    int idx = blockIdx.x * 256 + threadIdx.x;      // 245760 float4 items
    float4 xin = ((const float4*)X)[idx];
    __hip_bfloat16* o = Xb + (size_t)idx * 4;
    o[0] = __float2bfloat16(xin.x); o[1] = __float2bfloat16(xin.y);
    o[2] = __float2bfloat16(xin.z); o[3] = __float2bfloat16(xin.w);
}

// ---------------- transpose+cast W[k][n] f32 -> WT[n][k] bf16 ----------------
__global__ __launch_bounds__(256) void transpose_cast_w(
    const float* __restrict__ Wq, const float* __restrict__ Wk,
    const float* __restrict__ Wv, __hip_bfloat16* __restrict__ WT)
{
    __shared__ float t[32][33];
    const float* W = (blockIdx.z == 0) ? Wq : (blockIdx.z == 1) ? Wk : Wv;
    __hip_bfloat16* o = WT + (size_t)blockIdx.z * HH * HH;
    int kt = blockIdx.x * 32, nt = blockIdx.y * 32;
    int tx = threadIdx.x & 31, ty = threadIdx.x >> 5;   // ty 0..7
#pragma unroll
    for (int r = 0; r < 32; r += 8)
        t[ty + r][tx] = W[(size_t)(kt + ty + r) * HH + nt + tx];
    __syncthreads();
#pragma unroll
    for (int r = 0; r < 32; r += 8)
        o[(size_t)(nt + ty + r) * HH + kt + tx] = __float2bfloat16(t[tx][ty + r]);
}

// ---------------- MFMA GEMM: {q,k,v} = X @ W + b (bf16 in, f32 acc) ----------
__global__ __launch_bounds__(256) void gemm_qkv(
    const __hip_bfloat16* __restrict__ Xb, const __hip_bfloat16* __restrict__ WT,
    const float* __restrict__ bq, const float* __restrict__ bk,
    const float* __restrict__ bv,
    __hip_bfloat16* __restrict__ qb, __hip_bfloat16* __restrict__ kb,
    __hip_bfloat16* __restrict__ vb)
{
    __shared__ int4 sA[4][128];   // 8 KB
    __shared__ int4 sB[4][64];    // 4 KB
    int m0 = blockIdx.x * 128, n0 = blockIdx.y * 64, mat = blockIdx.z;
    const short* X = (const short*)Xb;
    const short* W = (const short*)WT + (size_t)mat * HH * HH;
    const float* bias = (mat == 0) ? bq : (mat == 1) ? bk : bv;
    int tid = threadIdx.x, w = tid >> 6, l = tid & 63;
    int wm = (w >> 1) * 64, wn = (w & 1) * 32;
    int khalf = l >> 4, lc = l & 15;

    f32x4 acc[4][2];
#pragma unroll
    for (int i = 0; i < 4; i++)
#pragma unroll
        for (int j = 0; j < 2; j++) acc[i][j] = (f32x4){0.f, 0.f, 0.f, 0.f};

    for (int k0 = 0; k0 < HH; k0 += 32) {
        __syncthreads();
        sA[w][l]      = *(const int4*)(X + (size_t)(m0 + l) * HH + k0 + w * 8);
        sA[w][l + 64] = *(const int4*)(X + (size_t)(m0 + l + 64) * HH + k0 + w * 8);
        sB[w][l]      = *(const int4*)(W + (size_t)(n0 + l) * HH + k0 + w * 8);
        __syncthreads();
        bf16x8 b0 = *(const bf16x8*)&sB[khalf][wn + lc];
        bf16x8 b1 = *(const bf16x8*)&sB[khalf][wn + 16 + lc];
#pragma unroll
        for (int mi = 0; mi < 4; mi++) {
            bf16x8 a = *(const bf16x8*)&sA[khalf][wm + mi * 16 + lc];
            acc[mi][0] = __builtin_amdgcn_mfma_f32_16x16x32_bf16(a, b0, acc[mi][0], 0, 0, 0);
            acc[mi][1] = __builtin_amdgcn_mfma_f32_16x16x32_bf16(a, b1, acc[mi][1], 0, 0, 0);
        }
    }

    int rg = (l >> 4) * 4;
    __hip_bfloat16* outm = (mat == 0) ? qb : (mat == 1) ? kb : vb;
#pragma unroll
    for (int ni = 0; ni < 2; ni++) {
        int gcol = n0 + wn + ni * 16 + lc;
        float bv_ = bias[gcol];
#pragma unroll
        for (int mi = 0; mi < 4; mi++) {
            int grow = m0 + wm + mi * 16 + rg;
            f32x4 a = acc[mi][ni];
            __hip_bfloat16* o = outm + (size_t)grow * HH + gcol;
            o[0]      = __float2bfloat16(a.x + bv_);
            o[HH]     = __float2bfloat16(a.y + bv_);
            o[2 * HH] = __float2bfloat16(a.z + bv_);
            o[3 * HH] = __float2bfloat16(a.w + bv_);
        }
    }
}

// ---------------- MFMA scores: S[b][h] = (Q_h K_h^T) * 0.125, f16 out -------
__global__ __launch_bounds__(256) void scores_gemm(
    const __hip_bfloat16* __restrict__ qb, const __hip_bfloat16* __restrict__ kb,
    _Float16* __restrict__ sc)
{
    __shared__ int4 sQ[8][160];   // 20.5 KB
    __shared__ int4 sK[8][160];
    int h = blockIdx.x, b = blockIdx.y;
    const short* Q = (const short*)qb + (size_t)b * SS * HH + h * DHEAD;
    const short* K = (const short*)kb + (size_t)b * SS * HH + h * DHEAD;
    int tid = threadIdx.x, w = tid >> 6, l = tid & 63;

    for (int idx = tid; idx < SS * 8; idx += 256) {
        int row = idx >> 3, ch = idx & 7;
        sQ[ch][row] = *(const int4*)(Q + (size_t)row * HH + ch * 8);
        sK[ch][row] = *(const int4*)(K + (size_t)row * HH + ch * 8);
    }
    __syncthreads();

    int wm = (w >> 1) * 80, wn = (w & 1) * 80;
    int khalf = l >> 4, lc = l & 15;
    f32x4 acc[5][5];
#pragma unroll
    for (int i = 0; i < 5; i++)
#pragma unroll
        for (int j = 0; j < 5; j++) acc[i][j] = (f32x4){0.f, 0.f, 0.f, 0.f};

#pragma unroll
    for (int s = 0; s < 2; s++) {
        int c = s * 4 + khalf;
        bf16x8 bf[5];
#pragma unroll
        for (int ni = 0; ni < 5; ni++)
            bf[ni] = *(const bf16x8*)&sK[c][wn + ni * 16 + lc];
#pragma unroll
        for (int mi = 0; mi < 5; mi++) {
            bf16x8 a = *(const bf16x8*)&sQ[c][wm + mi * 16 + lc];
#pragma unroll
            for (int ni = 0; ni < 5; ni++)
                acc[mi][ni] = __builtin_amdgcn_mfma_f32_16x16x32_bf16(a, bf[ni], acc[mi][ni], 0, 0, 0);
        }
    }

    int rg = (l >> 4) * 4;
    _Float16* base = sc + (size_t)(b * NHEAD + h) * SS * SS;
#pragma unroll
    for (int mi = 0; mi < 5; mi++) {
        int i0 = wm + mi * 16 + rg;
#pragma unroll
        for (int ni = 0; ni < 5; ni++) {
            int j = wn + ni * 16 + lc;
            f32x4 a = acc[mi][ni];
            base[(size_t)(i0 + 0) * SS + j] = (_Float16)(a.x * 0.125f);
            base[(size_t)(i0 + 1) * SS + j] = (_Float16)(a.y * 0.125f);
            base[(size_t)(i0 + 2) * SS + j] = (_Float16)(a.z * 0.125f);
            base[(size_t)(i0 + 3) * SS + j] = (_Float16)(a.w * 0.125f);
        }
    }
}

// ---------------- MFMA qek: qek[bi][h][d] = Wek_h^T q_h (bf16 out) ----------
// One wave per (16-row bi tile, head). A,B straight from global, no LDS.
__global__ __launch_bounds__(256) void qek_gemm(
    const __hip_bfloat16* __restrict__ qb, const float* __restrict__ Wek,
    __hip_bfloat16* __restrict__ qek)
{
    int task = blockIdx.x * 4 + (threadIdx.x >> 6);   // 0..959
    int l = threadIdx.x & 63;
    int mt = task / NHEAD, h = task - mt * NHEAD;
    int bi0 = mt * 16;
    int lr = l & 15, kg = l >> 4;
    const short* Q = (const short*)qb;

    // A frags (m = bi row): k-steps s=0,1
    bf16x8 a0 = *(const bf16x8*)(Q + (size_t)(bi0 + lr) * HH + h * DHEAD + kg * 8);
    bf16x8 a1 = *(const bf16x8*)(Q + (size_t)(bi0 + lr) * HH + h * DHEAD + 32 + kg * 8);

    short* O = (short*)qek;
#pragma unroll
    for (int nt = 0; nt < 4; nt++) {
        int d = nt * 16 + lr;                  // n = output depth index
        const float* wp = Wek + (size_t)d * HH + h * DHEAD + kg * 8;
        float4 w0 = *(const float4*)(wp);
        float4 w1 = *(const float4*)(wp + 4);
        float4 w2 = *(const float4*)(wp + 32);
        float4 w3 = *(const float4*)(wp + 36);
        bf16x8 b0, b1;
        b0[0]=f2bs(w0.x); b0[1]=f2bs(w0.y); b0[2]=f2bs(w0.z); b0[3]=f2bs(w0.w);
        b0[4]=f2bs(w1.x); b0[5]=f2bs(w1.y); b0[6]=f2bs(w1.z); b0[7]=f2bs(w1.w);
        b1[0]=f2bs(w2.x); b1[1]=f2bs(w2.y); b1[2]=f2bs(w2.z); b1[3]=f2bs(w2.w);
        b1[4]=f2bs(w3.x); b1[5]=f2bs(w3.y); b1[6]=f2bs(w3.z); b1[7]=f2bs(w3.w);
        f32x4 acc = (f32x4){0.f, 0.f, 0.f, 0.f};
        acc = __builtin_amdgcn_mfma_f32_16x16x32_bf16(a0, b0, acc, 0, 0, 0);
        acc = __builtin_amdgcn_mfma_f32_16x16x32_bf16(a1, b1, acc, 0, 0, 0);
        // C: col(lane&15)=d-in-tile handled via d; row = bi0 + kg*4 + r
        int row0 = bi0 + kg * 4;
#pragma unroll
        for (int r = 0; r < 4; r++)
            O[(size_t)(row0 + r) * HH + h * DHEAD + nt * 16 + lr] = f2bs(acc[r]);
    }
}

// ---------------- MFMA escore: sc[b,h,i,j] += 0.125 * e[b,i,j,:].qek[b,i,h,:] -
// One wave per (b,i). A = e (m=j, f32->bf16 in flight), B = qek row (n=h).
__global__ __launch_bounds__(256) void escore_add(
    const float* __restrict__ edge, const __hip_bfloat16* __restrict__ qek,
    _Float16* __restrict__ sc)
{
    int bi = blockIdx.x * 4 + (threadIdx.x >> 6);
    int l = threadIdx.x & 63;
    int b = bi / SS, i = bi - b * SS;
    int lr = l & 15, kg = l >> 4;
    const short* QE = (const short*)qek + (size_t)bi * HH;

    // B frags: n = h = lr (cols 12..15 read past row end -> defined ws garbage,
    // results unused); k = s*32 + kg*8
    bf16x8 qe0 = *(const bf16x8*)(QE + lr * DHEAD + kg * 8);
    bf16x8 qe1 = *(const bf16x8*)(QE + lr * DHEAD + 32 + kg * 8);

    const float* E = edge + (size_t)bi * SS * DEPTH;
    int h = lr, hc = (h < NHEAD) ? h : (NHEAD - 1);
    bool hvalid = (h < NHEAD);
    _Float16* srow = sc + ((size_t)(b * NHEAD + hc) * SS + i) * SS;

#pragma unroll 2
    for (int jt = 0; jt < 10; jt++) {
        const float* ep = E + (size_t)(jt * 16 + lr) * DEPTH + kg * 8;
        float4 e0 = *(const float4*)(ep);
        float4 e1 = *(const float4*)(ep + 4);
        float4 e2 = *(const float4*)(ep + 32);
        float4 e3 = *(const float4*)(ep + 36);
        bf16x8 a0, a1;
        a0[0]=f2bs(e0.x); a0[1]=f2bs(e0.y); a0[2]=f2bs(e0.z); a0[3]=f2bs(e0.w);
        a0[4]=f2bs(e1.x); a0[5]=f2bs(e1.y); a0[6]=f2bs(e1.z); a0[7]=f2bs(e1.w);
        a1[0]=f2bs(e2.x); a1[1]=f2bs(e2.y); a1[2]=f2bs(e2.z); a1[3]=f2bs(e2.w);
        a1[4]=f2bs(e3.x); a1[5]=f2bs(e3.y); a1[6]=f2bs(e3.z); a1[7]=f2bs(e3.w);
        f32x4 acc = (f32x4){0.f, 0.f, 0.f, 0.f};
        acc = __builtin_amdgcn_mfma_f32_16x16x32_bf16(a0, qe0, acc, 0, 0, 0);
        acc = __builtin_amdgcn_mfma_f32_16x16x32_bf16(a1, qe1, acc, 0, 0, 0);
        if (hvalid) {
            int j0 = jt * 16 + kg * 4;       // 4 consecutive j per lane
            _Float16* p = srow + j0;
            p[0] = (_Float16)((float)p[0] + 0.125f * acc[0]);
            p[1] = (_Float16)((float)p[1] + 0.125f * acc[1]);
            p[2] = (_Float16)((float)p[2] + 0.125f * acc[2]);
            p[3] = (_Float16)((float)p[3] + 0.125f * acc[3]);
        }
    }
}

// ---------------- Fused attention epilogue + LayerNorm ----------------
// One block per (b,i). Scores fully precomputed in sc (qk + e.qek, scaled);
// only qbek + mask applied here.
__global__ __launch_bounds__(256) void attn_kernel(
    const float* __restrict__ token, const float* __restrict__ edge,
    const int* __restrict__ mask,
    const __hip_bfloat16* __restrict__ q_ws, const _Float16* __restrict__ sc,
    const __hip_bfloat16* __restrict__ v_ws,
    const float* __restrict__ bek,
    const float* __restrict__ Wev, const float* __restrict__ bev,
    const float* __restrict__ ln_g, const float* __restrict__ ln_b,
    float* __restrict__ out)
{
    __shared__ float  s_q[HH];               // q row; reused as ctx_v after pass2
    __shared__ float  s_scores[NHEAD][SS];   // scores -> probs
    __shared__ float  s_pe[NHEAD][DEPTH];    // p . e
    __shared__ float  s_x[HH];               // pre-LN row
    __shared__ float  s_qbek[NHEAD];
    __shared__ int    s_mask[SS];
    __shared__ float  s_red[8];

    int bi = blockIdx.x;                     // b*S + i
    int b  = bi / SS;
    int i  = bi - b * SS;
    int tid = threadIdx.x;
    int w = tid >> 6, l = tid & 63;

    // ---- load q row + mask row ----
    for (int c = tid; c < HH; c += 256)
        s_q[c] = __bfloat162float(q_ws[(size_t)bi * HH + c]);
    if (tid < SS) s_mask[tid] = mask[(size_t)bi * SS + tid];
    __syncthreads();

    // qbek[h] = q_h . bek_h
    if (tid < NHEAD) {
        const float* qp = s_q + tid * DHEAD;
        const float* bp = bek + tid * DHEAD;
        float sum = 0.f;
#pragma unroll
        for (int c = 0; c < DHEAD; c++) sum += qp[c] * bp[c];
        s_qbek[tid] = sum;
    }
    __syncthreads();

    // ---- assemble scores from ws ----
    const _Float16* scp = sc + (size_t)(b * NHEAD) * (SS * SS) + (size_t)i * SS;
    for (int idx = tid; idx < NHEAD * SS; idx += 256) {
        int h = idx / SS, j = idx - h * SS;
        float qk = (float)scp[(size_t)h * (SS * SS) + j];
        s_scores[h][j] = s_mask[j] ? (qk + 0.125f * s_qbek[h]) : -10000.0f;
    }
    __syncthreads();

    // ---- softmax per head (wave w -> heads w, w+4, w+8); S=160 = 64+64+32 ----
    for (int h = w; h < NHEAD; h += 4) {
        float v0 = s_scores[h][l];
        float v1 = s_scores[h][l + 64];
        float v2 = (l < 32) ? s_scores[h][l + 128] : -INFINITY;
        float mx = fmaxf(v0, fmaxf(v1, v2));
#pragma unroll
        for (int mm = 32; mm >= 1; mm >>= 1) mx = fmaxf(mx, __shfl_xor(mx, mm, 64));
        float e0 = expf(v0 - mx), e1 = expf(v1 - mx);
        float e2 = (l < 32) ? expf(v2 - mx) : 0.f;
        float sm = e0 + e1 + e2;
#pragma unroll
        for (int mm = 32; mm >= 1; mm >>= 1) sm += __shfl_xor(sm, mm, 64);
        float inv = 1.0f / sm;
        s_scores[h][l]      = e0 * inv;
        s_scores[h][l + 64] = e1 * inv;
        if (l < 32) s_scores[h][l + 128] = e2 * inv;
    }
    __syncthreads();

    // ---- pass 2: wave w owns heads 3w..3w+2; lane = channel; dense ----
    const float* e_row = edge + (size_t)bi * SS * DEPTH;
    {
        int h0 = w * 3;
        float av0 = 0.f, av1 = 0.f, av2 = 0.f;
        float pe0 = 0.f, pe1 = 0.f, pe2 = 0.f;
        const __hip_bfloat16* vbp = v_ws + (size_t)b * SS * HH + h0 * DHEAD + l;
        const float* er = e_row + l;
        const float* p0r = &s_scores[h0][0];
        const float* p1r = &s_scores[h0 + 1][0];
        const float* p2r = &s_scores[h0 + 2][0];
#pragma unroll 4
        for (int j = 0; j < SS; j++) {
            float p0 = p0r[j], p1 = p1r[j], p2 = p2r[j];
            const __hip_bfloat16* vp = vbp + (size_t)j * HH;
            av0 += p0 * __bfloat162float(vp[0]);
            av1 += p1 * __bfloat162float(vp[DHEAD]);
            av2 += p2 * __bfloat162float(vp[2 * DHEAD]);
            float ev = er[(size_t)j * DEPTH];
            pe0 += p0 * ev; pe1 += p1 * ev; pe2 += p2 * ev;
        }
        s_pe[h0][l]     = pe0;
        s_pe[h0 + 1][l] = pe1;
        s_pe[h0 + 2][l] = pe2;
        s_q[h0 * DHEAD + l]       = av0;   // s_q reused as ctx_v
        s_q[(h0 + 1) * DHEAD + l] = av1;
        s_q[(h0 + 2) * DHEAD + l] = av2;
    }
    __syncthreads();

    // ---- ctx_e = pe_h @ Wev_h + bev ; residual add ----
    for (int mdx = tid; mdx < HH; mdx += 256) {
        int h = mdx >> 6;
        const float* pep = &s_pe[h][0];
        float sum = 0.f;
#pragma unroll
        for (int d = 0; d < DEPTH; d++) sum += pep[d] * Wev[(size_t)d * HH + mdx];
        float ctx = s_q[mdx] + (sum + bev[mdx]);
        s_x[mdx] = token[(size_t)bi * HH + mdx] + ctx;
    }
    __syncthreads();

    // ---- LayerNorm over H ----
    float lsum = 0.f, lsq = 0.f;
    for (int c = tid; c < HH; c += 256) {
        float x = s_x[c];
        lsum += x; lsq += x * x;
    }
#pragma unroll
    for (int mm = 32; mm >= 1; mm >>= 1) {
        lsum += __shfl_xor(lsum, mm, 64);
        lsq  += __shfl_xor(lsq,  mm, 64);
    }
    if (l == 0) { s_red[w] = lsum; s_red[4 + w] = lsq; }
    __syncthreads();
    float tsum = s_red[0] + s_red[1] + s_red[2] + s_red[3];
    float tsq  = s_red[4] + s_red[5] + s_red[6] + s_red[7];
    float mu  = tsum / HH;
    float var = tsq / HH - mu * mu;
    float rstd = rsqrtf(var + EPS_C);
    for (int c = tid; c < HH; c += 256)
        out[(size_t)bi * HH + c] = (s_x[c] - mu) * rstd * ln_g[c] + ln_b[c];
}

extern "C" void kernel_launch(void* const* d_in, const int* in_sizes, int n_in,
                              void* d_out, int out_size, void* d_ws, size_t ws_size,
                              hipStream_t stream) {
    const float* token = (const float*)d_in[0];
    const float* edge  = (const float*)d_in[1];
    const int*   mask  = (const int*)d_in[2];
    const float* Wq = (const float*)d_in[3];  const float* bq = (const float*)d_in[4];
    const float* Wk = (const float*)d_in[5];  const float* bk = (const float*)d_in[6];
    const float* Wv = (const float*)d_in[7];  const float* bv = (const float*)d_in[8];
    const float* Wek = (const float*)d_in[9];  const float* bek = (const float*)d_in[10];
    const float* Wev = (const float*)d_in[11]; const float* bev = (const float*)d_in[12];
    const float* ln_g = (const float*)d_in[13]; const float* ln_b = (const float*)d_in[14];
    float* out = (float*)d_out;

    // ws layout (10.875 MiB, proven): [qb][kb][vb][Xb][WT]
    // sc f16 (4.69 MiB) aliases [Xb..WT] (5.25 MiB) after gemm_qkv.
    // qek bf16 (1.875 MiB) aliases kb after scores_gemm (kb dead then).
    __hip_bfloat16* qb = (__hip_bfloat16*)d_ws;
    __hip_bfloat16* kb = qb + (size_t)BS * HH;
    __hip_bfloat16* vb = kb + (size_t)BS * HH;
    __hip_bfloat16* Xb = vb + (size_t)BS * HH;
    __hip_bfloat16* WT = Xb + (size_t)BS * HH;
    _Float16*       sc = (_Float16*)Xb;
    __hip_bfloat16* qek = kb;

    cast_x<<<(BS * HH / 4) / 256, 256, 0, stream>>>(token, Xb);
    transpose_cast_w<<<dim3(24, 24, 3), 256, 0, stream>>>(Wq, Wk, Wv, WT);
    gemm_qkv<<<dim3(BS / 128, HH / 64, 3), 256, 0, stream>>>(
        Xb, WT, bq, bk, bv, qb, kb, vb);
    scores_gemm<<<dim3(NHEAD, BB), 256, 0, stream>>>(qb, kb, sc);
    qek_gemm<<<240, 256, 0, stream>>>(qb, Wek, qek);
    escore_add<<<BS / 4, 256, 0, stream>>>(edge, qek, sc);
    attn_kernel<<<BS, 256, 0, stream>>>(token, edge, mask, qb, sc, vb,
                                        bek, Wev, bev, ln_g, ln_b, out);
}